// Round 1
// baseline (226000.488 us; speedup 1.0000x reference)
//
#include <hip/hip_runtime.h>
#include <math.h>

#define BB 256
#define TT 256
#define INW 256
#define HH 1024
#define LL 8
#define CSW 10
#define OUTW 64
#define GG 4112           // 4*H + 2*L
#define H6 170
#define KA 1282           // (IN+1) + (H+1)

__device__ __forceinline__ float sigmoidf_(float v) { return 1.0f / (1.0f + expf(-v)); }

// ---------------- generic fp32 tiled GEMM: C = act(A(MxK) * B(KxN) + bias) ----------------
// supports split-K along blockIdx.z (kChunk per split, partials at z*splitStride)
__global__ __launch_bounds__(256) void gemm_f32(
    const float* __restrict__ A, const float* __restrict__ Bm,
    const float* __restrict__ bias, float* __restrict__ C,
    int M, int N, int K, int ldc, int act, int kChunk, size_t splitStride)
{
    __shared__ float As[64][17];
    __shared__ float Bs[16][64];
    int tid = threadIdx.x;
    int tx = tid & 15, ty = tid >> 4;
    int m0 = blockIdx.y * 64, n0 = blockIdx.x * 64;
    int z = blockIdx.z;
    int kBeg = z * kChunk;
    int kEnd = K < kBeg + kChunk ? K : kBeg + kChunk;

    float acc[4][4];
#pragma unroll
    for (int i = 0; i < 4; ++i)
#pragma unroll
        for (int j = 0; j < 4; ++j) acc[i][j] = 0.0f;

    int am = tid >> 2, ak = (tid & 3) << 2;
    int bn = tid & 63, bk0 = (tid >> 6) << 2;

    for (int kt = kBeg; kt < kEnd; kt += 16) {
#pragma unroll
        for (int u = 0; u < 4; ++u) {
            int kk = kt + ak + u;
            As[am][ak + u] = (kk < kEnd) ? A[(size_t)(m0 + am) * K + kk] : 0.0f;
        }
#pragma unroll
        for (int u = 0; u < 4; ++u) {
            int kk = kt + bk0 + u;
            Bs[bk0 + u][bn] = (kk < kEnd && (n0 + bn) < N) ? Bm[(size_t)kk * N + n0 + bn] : 0.0f;
        }
        __syncthreads();
#pragma unroll
        for (int kk = 0; kk < 16; ++kk) {
            float av[4], bv[4];
#pragma unroll
            for (int i = 0; i < 4; ++i) av[i] = As[ty * 4 + i][kk];
#pragma unroll
            for (int j = 0; j < 4; ++j) bv[j] = Bs[kk][tx * 4 + j];
#pragma unroll
            for (int i = 0; i < 4; ++i)
#pragma unroll
                for (int j = 0; j < 4; ++j) acc[i][j] = fmaf(av[i], bv[j], acc[i][j]);
        }
        __syncthreads();
    }

#pragma unroll
    for (int i = 0; i < 4; ++i) {
        int row = m0 + ty * 4 + i;
        if (row >= M) continue;
#pragma unroll
        for (int j = 0; j < 4; ++j) {
            int col = n0 + tx * 4 + j;
            if (col >= N) continue;
            float v = acc[i][j];
            if (bias != nullptr && z == 0) v += bias[col];
            if (act == 1) v = v > 0.0f ? v : 0.0f;
            else if (act == 2) v = sigmoidf_(v);
            C[splitStride * (size_t)z + (size_t)row * ldc + col] = v;
        }
    }
}

// ---------------- once-per-launch weight prep ----------------
__global__ void build_wcomb(const float* __restrict__ kw, const float* __restrict__ rw,
                            float* __restrict__ Wc)
{
    size_t i = (size_t)blockIdx.x * 256 + threadIdx.x;
    if (i >= (size_t)KA * GG) return;
    int r = (int)(i / GG), g = (int)(i % GG);
    Wc[i] = (r < INW + 1) ? kw[(size_t)r * GG + g] : rw[(size_t)(r - (INW + 1)) * GG + g];
}

__global__ void build_bias(const float* __restrict__ kb, const float* __restrict__ rb,
                           float* __restrict__ bc)
{
    int i = blockIdx.x * 256 + threadIdx.x;
    if (i < GG) bc[i] = kb[i] + rb[i];
}

// convT[kk][o] = conv_w[o][kk]  (kk = c*CS + k, over H*CS)
__global__ void build_convT(const float* __restrict__ cw, float* __restrict__ ct)
{
    size_t i = (size_t)blockIdx.x * 256 + threadIdx.x;
    if (i >= (size_t)HH * HH * CSW) return;
    size_t kk = i / HH;
    int o = (int)(i % HH);
    ct[i] = cw[(size_t)o * (HH * CSW) + kk];
}

// ---------------- per-step kernels ----------------
// A = [x_t (256) | time (1) | h (1024) | time (1)]
__global__ void build_a(const float* __restrict__ x, const float* __restrict__ tim,
                        const float* __restrict__ h, float* __restrict__ A, int t)
{
    int b = blockIdx.y;
    int k = blockIdx.x * 256 + threadIdx.x;
    if (k >= KA) return;
    float v;
    if (k < INW)               v = x[((size_t)b * TT + t) * INW + k];
    else if (k == INW)         v = tim[(size_t)b * TT + t];
    else if (k < INW + 1 + HH) v = h[(size_t)b * HH + (k - INW - 1)];
    else                       v = tim[(size_t)b * TT + t];
    A[(size_t)b * KA + k] = v;
}

// softmax/cumsum gating, cell+hidden update, ring updates, ld, distance output
__global__ __launch_bounds__(256) void step_kernel(
    const float* __restrict__ xo, float* __restrict__ c, float* __restrict__ h,
    float* __restrict__ ringH, float* __restrict__ ringD, float* __restrict__ ld,
    float* __restrict__ dist, int t)
{
    int b = blockIdx.x, tid = threadIdx.x;
    __shared__ float fm[LL], im[LL];
    if (tid == 0) {
        const float* xr = xo + (size_t)b * GG;
        float m1 = -1e30f, m2 = -1e30f;
        for (int l = 0; l < LL; ++l) { m1 = fmaxf(m1, xr[l]); m2 = fmaxf(m2, xr[LL + l]); }
        float e1[LL], e2[LL], s1 = 0.0f, s2 = 0.0f;
        for (int l = 0; l < LL; ++l) {
            e1[l] = expf(xr[l] - m1); s1 += e1[l];
            e2[l] = expf(xr[LL + l] - m2); s2 += e2[l];
        }
        float cum = 0.0f, meanfm = 0.0f;
        for (int l = 0; l < LL; ++l) { cum += e1[l] / s1; fm[l] = cum; meanfm += cum; }
        float rc = 0.0f;
        for (int l = LL - 1; l >= 0; --l) { rc += e2[l] / s2; im[l] = rc; }
        float cur = 1.0f - meanfm / LL;
        int slot = t % CSW;
        ringD[slot * BB + b] = cur;
        dist[(size_t)t * BB + b] = cur;
        // ld = softmax_k(cumsum_k(tmp_dis))  with logical k -> phys slot (t+1+k)%CS
        float cd = 0.0f, cv[CSW], mx = -1e30f;
        for (int k = 0; k < CSW; ++k) {
            cd += ringD[((t + 1 + k) % CSW) * BB + b];
            cv[k] = cd; mx = fmaxf(mx, cd);
        }
        float ss = 0.0f;
        for (int k = 0; k < CSW; ++k) { cv[k] = expf(cv[k] - mx); ss += cv[k]; }
        for (int k = 0; k < CSW; ++k) ld[b * CSW + k] = cv[k] / ss;
    }
    __syncthreads();
    int slot = t % CSW;
    const float* xg = xo + (size_t)b * GG + 2 * LL;
    for (int e = tid; e < HH; e += 256) {
        int l = e >> 7;  // CHUNK = 128
        float f  = sigmoidf_(xg[e]);
        float ig = sigmoidf_(xg[HH + e]);
        float og = sigmoidf_(xg[2 * HH + e]);
        float ci = tanhf(xg[3 * HH + e]);
        size_t idx = (size_t)b * HH + e;
        float cl = c[idx];
        float F = fm[l], I = im[l], OV = F * I;
        float cn = OV * (f * cl + ig * ci) + (F - OV) * cl + (I - OV) * ci;
        float hn = og * tanhf(cn);
        c[idx] = cn;
        h[idx] = hn;
        ringH[(size_t)slot * BB * HH + idx] = hn;
    }
}

// lh[b, c*CS+k] = ringH[phys(k)][b,c] * ld[b,k];  mean_lh[b,c] = mean_k
__global__ void lh_mean_kernel(const float* __restrict__ ringH, const float* __restrict__ ld,
                               float* __restrict__ lh, float* __restrict__ mlh, int t)
{
    int b = blockIdx.y;
    int cc = blockIdx.x * 256 + threadIdx.x;
    float ldv[CSW];
#pragma unroll
    for (int k = 0; k < CSW; ++k) ldv[k] = ld[b * CSW + k];
    float s = 0.0f;
#pragma unroll
    for (int k = 0; k < CSW; ++k) {
        int phys = (t + 1 + k) % CSW;
        float v = ringH[(size_t)phys * BB * HH + (size_t)b * HH + cc] * ldv[k];
        lh[(size_t)b * (HH * CSW) + (size_t)cc * CSW + k] = v;
        s += v;
    }
    mlh[(size_t)b * HH + cc] = s * (1.0f / CSW);
}

// conv_out = sum(partials) + conv_b;  rnn = theme*conv_out + h
__global__ void local_rnn_kernel(const float* __restrict__ part, const float* __restrict__ convb,
                                 const float* __restrict__ theme, const float* __restrict__ h,
                                 float* __restrict__ rnn)
{
    size_t i = (size_t)blockIdx.x * 256 + threadIdx.x;
    if (i >= (size_t)BB * HH) return;
    int col = (int)(i % HH);
    const size_t S = (size_t)BB * HH;
    float conv = part[i] + part[i + S] + part[i + 2 * S] + part[i + 3 * S] + convb[col];
    rnn[i] = theme[i] * conv + h[i];
}

extern "C" void kernel_launch(void* const* d_in, const int* in_sizes, int n_in,
                              void* d_out, int out_size, void* d_ws, size_t ws_size,
                              hipStream_t stream)
{
    const float* x   = (const float*)d_in[0];
    const float* tim = (const float*)d_in[1];
    const float* kw  = (const float*)d_in[2];
    const float* kb  = (const float*)d_in[3];
    const float* rw  = (const float*)d_in[4];
    const float* rb  = (const float*)d_in[5];
    const float* sw  = (const float*)d_in[6];
    const float* sb  = (const float*)d_in[7];
    const float* rsw = (const float*)d_in[8];
    const float* rsb = (const float*)d_in[9];
    const float* cw  = (const float*)d_in[10];
    const float* cb  = (const float*)d_in[11];
    const float* ow  = (const float*)d_in[12];
    const float* ob  = (const float*)d_in[13];
    float* out  = (float*)d_out;
    float* dist = out + (size_t)BB * TT * OUTW;

    float* ws = (float*)d_ws;
    size_t off = 0;
    auto alloc = [&](size_t n) { float* p = ws + off; off += n; return p; };
    float* h     = alloc((size_t)BB * HH);
    float* c     = alloc((size_t)BB * HH);
    float* ringH = alloc((size_t)CSW * BB * HH);
    float* ringD = alloc((size_t)CSW * BB);
    size_t zeroFloats = off;                       // state region zeroed per call
    float* xo    = alloc((size_t)BB * GG);
    float* ld    = alloc((size_t)BB * CSW);
    float* Abuf  = alloc((size_t)BB * KA);
    float* mlh   = alloc((size_t)BB * HH);
    float* th1   = alloc((size_t)BB * H6);
    float* th    = alloc((size_t)BB * HH);
    float* lh    = alloc((size_t)BB * HH * CSW);
    float* part  = alloc((size_t)4 * BB * HH);
    float* rnn   = alloc((size_t)BB * HH);
    float* Wc    = alloc((size_t)KA * GG);
    float* bc    = alloc((size_t)GG);
    float* cT    = alloc((size_t)HH * HH * CSW);
    if (ws_size < off * sizeof(float)) return;     // ws probe: output stays 0 -> absmax ~0.83

    hipMemsetAsync(ws, 0, zeroFloats * sizeof(float), stream);

    build_wcomb<<<(int)(((size_t)KA * GG + 255) / 256), 256, 0, stream>>>(kw, rw, Wc);
    build_bias<<<(GG + 255) / 256, 256, 0, stream>>>(kb, rb, bc);
    build_convT<<<(int)(((size_t)HH * HH * CSW + 255) / 256), 256, 0, stream>>>(cw, cT);

    for (int t = 0; t < TT; ++t) {
        build_a<<<dim3((KA + 255) / 256, BB), 256, 0, stream>>>(x, tim, h, Abuf, t);
        // xo = A @ Wcomb + (kernel_b + rec_b)
        gemm_f32<<<dim3((GG + 63) / 64, BB / 64, 1), 256, 0, stream>>>(
            Abuf, Wc, bc, xo, BB, GG, KA, GG, 0, KA, 0);
        step_kernel<<<BB, 256, 0, stream>>>(xo, c, h, ringH, ringD, ld, dist, t);
        lh_mean_kernel<<<dim3(HH / 256, BB), 256, 0, stream>>>(ringH, ld, lh, mlh, t);
        // theme1 = relu(mean_lh @ scale_w + scale_b)
        gemm_f32<<<dim3((H6 + 63) / 64, BB / 64, 1), 256, 0, stream>>>(
            mlh, sw, sb, th1, BB, H6, HH, H6, 1, HH, 0);
        // theme = sigmoid(theme1 @ rescale_w + rescale_b)
        gemm_f32<<<dim3(HH / 64, BB / 64, 1), 256, 0, stream>>>(
            th1, rsw, rsb, th, BB, HH, H6, HH, 2, H6, 0);
        // conv partials: lh(256x10240) @ convT(10240x1024), split-K=4
        gemm_f32<<<dim3(HH / 64, BB / 64, 4), 256, 0, stream>>>(
            lh, cT, nullptr, part, BB, HH, HH * CSW, HH, 0, (HH * CSW) / 4, (size_t)BB * HH);
        local_rnn_kernel<<<(int)(((size_t)BB * HH + 255) / 256), 256, 0, stream>>>(
            part, cb, th, h, rnn);
        // out_t = sigmoid(rnn @ out_w + out_b), strided into d_out[b, t, :]
        gemm_f32<<<dim3(1, BB / 64, 1), 256, 0, stream>>>(
            rnn, ow, ob, out + (size_t)t * OUTW, BB, OUTW, HH, TT * OUTW, 2, HH, 0);
    }
}

// Round 3
// 42574.716 us; speedup vs baseline: 5.3083x; 5.3083x over previous
//
#include <hip/hip_runtime.h>
#include <math.h>

#define BB 256
#define TT 256
#define INW 256
#define HH 1024
#define LL 8
#define CSW 10
#define OUTW 64
#define GG 4112
#define KSEG 1344          // 288 (x,t,t,pad) + 1024 (h) + 32 pad
#define KTRIP 4032         // 3 * KSEG  (Ahi*Whi + Ahi*Wlo + Alo*Whi)
#define NPAD 4224          // 4112 padded to 33*128
#define BH (BB * HH)

typedef __attribute__((ext_vector_type(8))) short short8;
typedef __attribute__((ext_vector_type(4))) float f32x4;

__device__ __forceinline__ float bf2f(ushort u) {
    union { float f; unsigned int i; } v; v.i = ((unsigned int)u) << 16; return v.f;
}
__device__ __forceinline__ ushort f2bf(float f) {
    union { float f; unsigned int i; } v; v.f = f;
    unsigned int r = v.i + 0x7FFFu + ((v.i >> 16) & 1u);
    return (ushort)(r >> 16);
}
__device__ __forceinline__ float sigf(float v) { return 1.0f / (1.0f + expf(-v)); }

// ================= generic bf16 MFMA GEMM =================
// C(MxN) = epilogue(A(MxK) * B(KxN) + bias);  B passed TRANSPOSED: BT[N][K].
// AMODE 0: plain bf16 A (row stride lda); rows are chunk-local
// AMODE 1: recurrent gather at step t: K=4032 triple-split
//          [x|t|t|pad|hHi|pad] ⊗ Whi  |  same ⊗ Wlo  |  [xLo|..|hLo|..] ⊗ Whi
//          x/time loaded fp32 and hi/lo-split on the fly; h from ring slot (t+8)%RING
// AMODE 2: conv gather: A[m][k=ks*1024+c] = hRing[(tBase+tt+ks)%RING][b][c] * ldw[m][ks]
// EPI 0: fp32 +bias   1: relu->bf16   2: sigmoid->bf16
// EPI 3: rnn = TH*(v+bias) + h_t -> bf16
// EPI 4: out[b][tBase+tt][col] = sigmoid(v+bias) -> fp32
template<int WR, int WC, int AMODE, int EPI>
__global__ __launch_bounds__(WR * WC * 64) void mm_kernel(
    const ushort* __restrict__ A, const float* __restrict__ xf,
    const float* __restrict__ tf, const ushort* __restrict__ hR,
    const ushort* __restrict__ hLo,
    const ushort* __restrict__ BT, const float* __restrict__ bias,
    void* __restrict__ Cp, const float* __restrict__ ldw,
    const ushort* __restrict__ TH, float* __restrict__ outp,
    int lda, int ldb, int ldc, int K, int t, int RING, int tBase)
{
    constexpr int BM = WR * 64, BN = WC * 64, NT = WR * WC * 64, LS = 72;
    __shared__ ushort As[BM * LS];
    __shared__ ushort Bs[BN * LS];
    const int tid = threadIdx.x;
    const int lane = tid & 63, wave = tid >> 6;
    const int wr = wave / WC, wc = wave % WC;
    const int m0 = blockIdx.y * BM, n0 = blockIdx.x * BN;
    f32x4 acc[4][4] = {};

    for (int kt = 0; kt < K; kt += 64) {
        // ---- stage A tile (BM x 64) ----
#pragma unroll
        for (int i = 0; i < BM * 8 / NT; ++i) {
            int id = tid + i * NT;
            int r = id >> 3, cc = id & 7;
            int k = kt + cc * 8;
            short8 v;
            if (AMODE == 0) {
                v = *(const short8*)(A + (size_t)(m0 + r) * lda + k);
            } else if (AMODE == 1) {
                int sel = k / KSEG, kr = k - sel * KSEG;   // 64-tiles never cross KSEG
                bool lo = (sel == 2);
                if (kr < 288) {
                    float xv[8];
                    int b = m0 + r;
                    if (kr < 256) {
                        const float* src = xf + ((size_t)b * TT + t) * INW + kr;
#pragma unroll
                        for (int j = 0; j < 8; ++j) xv[j] = src[j];
                    } else if (kr == 256) {
                        float tv = tf[(size_t)b * TT + t];
                        xv[0] = tv; xv[1] = tv;
#pragma unroll
                        for (int j = 2; j < 8; ++j) xv[j] = 0.f;
                    } else {
#pragma unroll
                        for (int j = 0; j < 8; ++j) xv[j] = 0.f;
                    }
                    ushort* po = (ushort*)&v;
#pragma unroll
                    for (int j = 0; j < 8; ++j) {
                        ushort hi = f2bf(xv[j]);
                        po[j] = lo ? f2bf(xv[j] - bf2f(hi)) : hi;
                    }
                } else if (kr < 1312) {
                    const ushort* src = lo
                        ? hLo + (size_t)(m0 + r) * HH + (kr - 288)
                        : hR + (size_t)((t + 8) % RING) * BH + (size_t)(m0 + r) * HH + (kr - 288);
                    v = *(const short8*)src;
                } else {
                    ushort* pz = (ushort*)&v;
#pragma unroll
                    for (int j = 0; j < 8; ++j) pz[j] = 0;
                }
            } else {  // AMODE 2: conv gather
                int ks = k >> 10, c = k & 1023;
                int tt = m0 >> 8, b = (m0 & 255) + r;
                int slot = (tBase + tt + ks) % RING;
                short8 hv = *(const short8*)(hR + (size_t)slot * BH + (size_t)b * HH + c);
                float s = ldw[((size_t)tt * 256 + b) * CSW + ks];
                ushort* pv = (ushort*)&hv;
                ushort* po = (ushort*)&v;
#pragma unroll
                for (int j = 0; j < 8; ++j) po[j] = f2bf(bf2f(pv[j]) * s);
            }
            *(short8*)(As + r * LS + cc * 8) = v;
        }
        // ---- stage B tile (BN x 64 of BT) ----
#pragma unroll
        for (int i = 0; i < BN * 8 / NT; ++i) {
            int id = tid + i * NT;
            int n = id >> 3, cc = id & 7;
            *(short8*)(Bs + n * LS + cc * 8) =
                *(const short8*)(BT + (size_t)(n0 + n) * ldb + kt + cc * 8);
        }
        __syncthreads();
        // ---- MFMA ----
#pragma unroll
        for (int kf = 0; kf < 2; ++kf) {
            short8 aF[4], bF[4];
#pragma unroll
            for (int mi = 0; mi < 4; ++mi)
                aF[mi] = *(const short8*)(As + (wr * 64 + mi * 16 + (lane & 15)) * LS + kf * 32 + (lane >> 4) * 8);
#pragma unroll
            for (int ni = 0; ni < 4; ++ni)
                bF[ni] = *(const short8*)(Bs + (wc * 64 + ni * 16 + (lane & 15)) * LS + kf * 32 + (lane >> 4) * 8);
#pragma unroll
            for (int mi = 0; mi < 4; ++mi)
#pragma unroll
                for (int ni = 0; ni < 4; ++ni)
                    acc[mi][ni] = __builtin_amdgcn_mfma_f32_16x16x32_bf16(aF[mi], bF[ni], acc[mi][ni], 0, 0, 0);
        }
        __syncthreads();
    }
    // ---- epilogue ----
#pragma unroll
    for (int mi = 0; mi < 4; ++mi) {
#pragma unroll
        for (int ni = 0; ni < 4; ++ni) {
#pragma unroll
            for (int j = 0; j < 4; ++j) {
                int row = m0 + wr * 64 + mi * 16 + ((lane >> 4) << 2) + j;
                int col = n0 + wc * 64 + ni * 16 + (lane & 15);
                float v = acc[mi][ni][j];
                if (bias) v += bias[col];
                if (EPI == 0) {
                    ((float*)Cp)[(size_t)row * ldc + col] = v;
                } else if (EPI == 1) {
                    ((ushort*)Cp)[(size_t)row * ldc + col] = f2bf(v > 0.f ? v : 0.f);
                } else if (EPI == 2) {
                    ((ushort*)Cp)[(size_t)row * ldc + col] = f2bf(sigf(v));
                } else if (EPI == 3) {
                    int tt = row >> 8, b = row & 255;
                    int slot = (tBase + tt + 9) % RING;
                    float th = bf2f(TH[(size_t)row * HH + col]);
                    float h  = bf2f(hR[(size_t)slot * BH + (size_t)b * HH + col]);
                    ((ushort*)Cp)[(size_t)row * ldc + col] = f2bf(th * v + h);
                } else {
                    int tt = tBase + (row >> 8), b = row & 255;
                    outp[((size_t)b * TT + tt) * OUTW + col] = sigf(v);
                }
            }
        }
    }
}

// ================= weight prep =================
__global__ void build_wct(const float* __restrict__ kw, const float* __restrict__ rw,
                          ushort* __restrict__ WcT)
{
    size_t i = (size_t)blockIdx.x * 256 + threadIdx.x;
    if (i >= (size_t)NPAD * KTRIP) return;
    int n = (int)(i / KTRIP), k = (int)(i % KTRIP);
    int sel = k / KSEG, kr = k - sel * KSEG;
    float w = 0.f;
    if (n < GG) {
        if (kr < 256)           w = kw[(size_t)kr * GG + n];
        else if (kr == 256)     w = kw[(size_t)256 * GG + n];
        else if (kr == 257)     w = rw[(size_t)1024 * GG + n];
        else if (kr >= 288 && kr < 1312) w = rw[(size_t)(kr - 288) * GG + n];
    }
    ushort hi = f2bf(w);
    WcT[i] = (sel == 1) ? f2bf(w - bf2f(hi)) : hi;
}

__global__ void build_bc(const float* __restrict__ kb, const float* __restrict__ rb,
                         float* __restrict__ bc)
{
    int i = blockIdx.x * 256 + threadIdx.x;
    if (i < NPAD) bc[i] = (i < GG) ? kb[i] + rb[i] : 0.f;
}

__global__ void build_ctt(const float* __restrict__ cw, ushort* __restrict__ ctT)
{
    size_t i = (size_t)blockIdx.x * 256 + threadIdx.x;
    if (i >= (size_t)HH * HH * CSW) return;
    int o = (int)(i / (HH * CSW)), rest = (int)(i % (HH * CSW));
    int k = rest >> 10, c = rest & 1023;
    ctT[i] = f2bf(cw[((size_t)o * HH + c) * CSW + k]);
}

__global__ void build_swt(const float* __restrict__ sw, const float* __restrict__ sb,
                          ushort* __restrict__ swT, float* __restrict__ sbP)
{
    int i = blockIdx.x * 256 + threadIdx.x;
    if (i < 256 * 1024) {
        int n = i >> 10, k = i & 1023;
        swT[i] = f2bf(n < 170 ? sw[(size_t)k * 170 + n] : 0.f);
    }
    if (i < 256) sbP[i] = (i < 170) ? sb[i] : 0.f;
}

__global__ void build_rswt(const float* __restrict__ rsw, ushort* __restrict__ rswT)
{
    int i = blockIdx.x * 256 + threadIdx.x;
    if (i >= 1024 * 256) return;
    int n = i >> 8, k = i & 255;
    rswT[i] = f2bf(k < 170 ? rsw[(size_t)k * HH + n] : 0.f);
}

__global__ void build_owt(const float* __restrict__ ow, ushort* __restrict__ owT)
{
    int i = blockIdx.x * 256 + threadIdx.x;
    if (i >= OUTW * HH) return;
    int n = i >> 10, k = i & 1023;
    owT[i] = f2bf(ow[(size_t)k * OUTW + n]);
}

// ================= per-step pointwise =================
__global__ __launch_bounds__(256) void step_kernel(
    const float* __restrict__ xo, float* __restrict__ c,
    ushort* __restrict__ hR, ushort* __restrict__ hLo,
    float* __restrict__ dist, int t, int RING)
{
    int b = blockIdx.x, tid = threadIdx.x;
    __shared__ float fm[LL], im[LL];
    if (tid == 0) {
        const float* xr = xo + (size_t)b * NPAD;
        float m1 = -1e30f, m2 = -1e30f;
        for (int l = 0; l < LL; ++l) { m1 = fmaxf(m1, xr[l]); m2 = fmaxf(m2, xr[LL + l]); }
        float e1[LL], e2[LL], s1 = 0.f, s2 = 0.f;
        for (int l = 0; l < LL; ++l) {
            e1[l] = expf(xr[l] - m1); s1 += e1[l];
            e2[l] = expf(xr[LL + l] - m2); s2 += e2[l];
        }
        float cum = 0.f, mean = 0.f;
        for (int l = 0; l < LL; ++l) { cum += e1[l] / s1; fm[l] = cum; mean += cum; }
        float rc = 0.f;
        for (int l = LL - 1; l >= 0; --l) { rc += e2[l] / s2; im[l] = rc; }
        dist[(size_t)t * BB + b] = 1.0f - mean / LL;
    }
    __syncthreads();
    const float* xg = xo + (size_t)b * NPAD + 2 * LL;
    int slot = (t + 9) % RING;
    for (int e = tid; e < HH; e += 256) {
        int l = e >> 7;
        float f  = sigf(xg[e]);
        float ig = sigf(xg[HH + e]);
        float og = sigf(xg[2 * HH + e]);
        float ci = tanhf(xg[3 * HH + e]);
        size_t idx = (size_t)b * HH + e;
        float cl = c[idx];
        float F = fm[l], I = im[l], OV = F * I;
        float cn = OV * (f * cl + ig * ci) + (F - OV) * cl + (I - OV) * ci;
        float hn = og * tanhf(cn);
        c[idx] = cn;
        ushort hi = f2bf(hn);
        hR[(size_t)slot * BH + idx] = hi;
        hLo[idx] = f2bf(hn - bf2f(hi));
    }
}

// ================= chunk helpers =================
__global__ void ld_chunk_kernel(const float* __restrict__ dist, float* __restrict__ ldC,
                                int tBase, int Mloc)
{
    int id = blockIdx.x * 256 + threadIdx.x;
    if (id >= Mloc) return;
    int t = tBase + (id >> 8), b = id & 255;
    float cv[CSW], cum = 0.f, mx = -1e30f;
#pragma unroll
    for (int k = 0; k < CSW; ++k) {
        int ts = t - 9 + k;
        cum += (ts >= 0) ? dist[(size_t)ts * BB + b] : 0.f;
        cv[k] = cum; mx = fmaxf(mx, cum);
    }
    float ss = 0.f;
#pragma unroll
    for (int k = 0; k < CSW; ++k) { cv[k] = expf(cv[k] - mx); ss += cv[k]; }
    float inv = 1.0f / ss;
#pragma unroll
    for (int k = 0; k < CSW; ++k) ldC[(size_t)id * CSW + k] = cv[k] * inv;
}

__global__ void mlh_kernel(const ushort* __restrict__ hR, const float* __restrict__ ldC,
                           ushort* __restrict__ MLH, int tBase, int RING)
{
    size_t id = (size_t)blockIdx.x * 256 + threadIdx.x;   // over Mloc*128
    int m = (int)(id >> 7);
    int c0 = ((int)(id & 127)) << 3;
    int t = tBase + (m >> 8), b = m & 255;
    float acc[8] = {};
#pragma unroll
    for (int k = 0; k < CSW; ++k) {
        float s = ldC[(size_t)m * CSW + k];
        int slot = (t + k) % RING;
        short8 hv = *(const short8*)(hR + (size_t)slot * BH + (size_t)b * HH + c0);
        ushort* pv = (ushort*)&hv;
#pragma unroll
        for (int j = 0; j < 8; ++j) acc[j] += bf2f(pv[j]) * s;
    }
#pragma unroll
    for (int j = 0; j < 8; ++j) MLH[(size_t)m * HH + c0 + j] = f2bf(acc[j] * 0.1f);
}

// ================= launch =================
extern "C" void kernel_launch(void* const* d_in, const int* in_sizes, int n_in,
                              void* d_out, int out_size, void* d_ws, size_t ws_size,
                              hipStream_t stream)
{
    const float* x   = (const float*)d_in[0];
    const float* tim = (const float*)d_in[1];
    const float* kw  = (const float*)d_in[2];
    const float* kb  = (const float*)d_in[3];
    const float* rw  = (const float*)d_in[4];
    const float* rb  = (const float*)d_in[5];
    const float* sw  = (const float*)d_in[6];
    const float* sb  = (const float*)d_in[7];
    const float* rsw = (const float*)d_in[8];
    const float* rsb = (const float*)d_in[9];
    const float* cw  = (const float*)d_in[10];
    const float* cb  = (const float*)d_in[11];
    const float* ow  = (const float*)d_in[12];
    const float* ob  = (const float*)d_in[13];
    float* out  = (float*)d_out;
    float* dist = out + (size_t)BB * TT * OUTW;

    // ---- adaptive chunk size against ws_size ----
    auto planSize = [&](int tch) -> size_t {
        size_t o = 0;
        auto al = [&](size_t bytes) { o += (bytes + 255) & ~(size_t)255; };
        int ring = tch + 9;
        al((size_t)ring * BH * 2);             // hRing
        al((size_t)BH * 2);                    // hLo
        al((size_t)BH * 4);                    // c
        al((size_t)NPAD * KTRIP * 2);          // WcT
        al((size_t)NPAD * 4);                  // bc
        al((size_t)BB * NPAD * 4);             // xo
        al((size_t)tch * 256 * CSW * 4);       // ldC
        al((size_t)HH * HH * CSW * 2);         // ctT
        al((size_t)256 * 1024 * 2);            // swT
        al((size_t)256 * 4);                   // sbP
        al((size_t)1024 * 256 * 2);            // rswT
        al((size_t)OUTW * HH * 2);             // owT
        al((size_t)tch * 256 * HH * 2);        // MLH / RNN
        al((size_t)tch * 256 * 256 * 2);       // TH1
        al((size_t)tch * 256 * HH * 2);        // TH
        return o;
    };
    const int cands[5] = {64, 32, 16, 8, 4};
    int TCH = 0;
    for (int ci = 0; ci < 5; ++ci)
        if (planSize(cands[ci]) <= ws_size) { TCH = cands[ci]; break; }
    if (TCH == 0) return;   // diagnostic: output stays zero -> absmax ~0.83
    const int RING = TCH + 9;
    const int Mloc = TCH * 256;

    char* base = (char*)d_ws;
    size_t off = 0;
    auto alloc = [&](size_t bytes) { char* p = base + off; off += (bytes + 255) & ~(size_t)255; return p; };
    ushort* hRing = (ushort*)alloc((size_t)RING * BH * 2);
    ushort* hLo   = (ushort*)alloc((size_t)BH * 2);
    float*  c     = (float*) alloc((size_t)BH * 4);
    ushort* WcT   = (ushort*)alloc((size_t)NPAD * KTRIP * 2);
    float*  bc    = (float*) alloc((size_t)NPAD * 4);
    float*  xo    = (float*) alloc((size_t)BB * NPAD * 4);
    float*  ldC   = (float*) alloc((size_t)TCH * 256 * CSW * 4);
    ushort* ctT   = (ushort*)alloc((size_t)HH * HH * CSW * 2);
    ushort* swT   = (ushort*)alloc((size_t)256 * 1024 * 2);
    float*  sbP   = (float*) alloc((size_t)256 * 4);
    ushort* rswT  = (ushort*)alloc((size_t)1024 * 256 * 2);
    ushort* owT   = (ushort*)alloc((size_t)OUTW * HH * 2);
    ushort* MLH   = (ushort*)alloc((size_t)TCH * 256 * HH * 2);
    ushort* TH1   = (ushort*)alloc((size_t)TCH * 256 * 256 * 2);
    ushort* TH    = (ushort*)alloc((size_t)TCH * 256 * HH * 2);
    ushort* RNN   = MLH;

    // state init
    hipMemsetAsync(hRing, 0, (size_t)9 * BH * 2, stream);
    hipMemsetAsync(hLo, 0, (size_t)BH * 2, stream);
    hipMemsetAsync(c, 0, (size_t)BH * 4, stream);

    // weight prep
    build_wct<<<(int)(((size_t)NPAD * KTRIP + 255) / 256), 256, 0, stream>>>(kw, rw, WcT);
    build_bc<<<(NPAD + 255) / 256, 256, 0, stream>>>(kb, rb, bc);
    build_ctt<<<(int)(((size_t)HH * HH * CSW + 255) / 256), 256, 0, stream>>>(cw, ctT);
    build_swt<<<(256 * 1024 + 255) / 256, 256, 0, stream>>>(sw, sb, swT, sbP);
    build_rswt<<<(1024 * 256 + 255) / 256, 256, 0, stream>>>(rsw, rswT);
    build_owt<<<(OUTW * HH + 255) / 256, 256, 0, stream>>>(ow, owT);

    for (int tBase = 0; tBase < TT; tBase += TCH) {
        // ---- scan steps of this chunk ----
        for (int t = tBase; t < tBase + TCH; ++t) {
            mm_kernel<1, 2, 1, 0><<<dim3(NPAD / 128, 4), 128, 0, stream>>>(
                nullptr, x, tim, hRing, hLo, WcT, bc, xo, nullptr, nullptr, nullptr,
                0, KTRIP, NPAD, KTRIP, t, RING, 0);
            step_kernel<<<BB, 256, 0, stream>>>(xo, c, hRing, hLo, dist, t, RING);
        }
        // ---- batched phase-2 for this chunk ----
        ld_chunk_kernel<<<Mloc / 256, 256, 0, stream>>>(dist, ldC, tBase, Mloc);
        mlh_kernel<<<Mloc / 2, 256, 0, stream>>>(hRing, ldC, MLH, tBase, RING);
        // theme1 = relu(MLH @ scale_w + sb)   [Mloc x 256(pad170) x K1024]
        mm_kernel<2, 2, 0, 1><<<dim3(2, Mloc / 128), 256, 0, stream>>>(
            MLH, nullptr, nullptr, nullptr, nullptr, swT, sbP, TH1, nullptr, nullptr, nullptr,
            1024, 1024, 256, 1024, 0, RING, tBase);
        // theme = sigmoid(TH1 @ rescale_w + rsb)  [Mloc x 1024 x K256]
        mm_kernel<2, 2, 0, 2><<<dim3(8, Mloc / 128), 256, 0, stream>>>(
            TH1, nullptr, nullptr, nullptr, nullptr, rswT, rsb, TH, nullptr, nullptr, nullptr,
            256, 256, 1024, 256, 0, RING, tBase);
        // rnn = TH*(conv+cb) + h   [Mloc x 1024 x K10240], A gathered on the fly
        mm_kernel<2, 2, 2, 3><<<dim3(8, Mloc / 128), 256, 0, stream>>>(
            nullptr, nullptr, nullptr, hRing, nullptr, ctT, cb, RNN, ldC, TH, nullptr,
            0, HH * CSW, 1024, HH * CSW, 0, RING, tBase);
        // output = sigmoid(RNN @ out_w + ob)  [Mloc x 64 x K1024]
        mm_kernel<4, 1, 0, 4><<<dim3(1, Mloc / 256), 256, 0, stream>>>(
            RNN, nullptr, nullptr, nullptr, nullptr, owT, ob, nullptr, nullptr, nullptr, out,
            1024, 1024, 0, 1024, 0, RING, tBase);
    }
}

// Round 4
// 14240.974 us; speedup vs baseline: 15.8697x; 2.9896x over previous
//
#include <hip/hip_runtime.h>
#include <math.h>

#define BB 256
#define TT 256
#define INW 256
#define HH 1024
#define LL 8
#define CSW 10
#define OUTW 64
#define GG 4112
#define KSEG 1344          // 288 (x,t,t,pad) + 1024 (h) + 32 pad
#define KTRIP 4032         // 3 * KSEG  (Ahi*Whi + Ahi*Wlo + Alo*Whi)
#define NPAD 4224          // 4112 padded to 33*128
#define BH (BB * HH)

typedef __attribute__((ext_vector_type(8))) short short8;
typedef __attribute__((ext_vector_type(4))) float f32x4;

__device__ __forceinline__ float bf2f(ushort u) {
    union { float f; unsigned int i; } v; v.i = ((unsigned int)u) << 16; return v.f;
}
__device__ __forceinline__ ushort f2bf(float f) {
    union { float f; unsigned int i; } v; v.f = f;
    unsigned int r = v.i + 0x7FFFu + ((v.i >> 16) & 1u);
    return (ushort)(r >> 16);
}
__device__ __forceinline__ float sigf(float v) { return 1.0f / (1.0f + expf(-v)); }

// ================= generic bf16 MFMA GEMM, reg-prefetch double-buffered ==========
// C(MxN) = epilogue(A(MxK)*B(KxN) + bias);  B passed TRANSPOSED: BT[N][K-global].
// AMODE 0: plain bf16 A (row stride lda is NOT used; rows contiguous at ldaA)
// AMODE 1: recurrent gather at step t, ONE K-segment (zSel from swizzled blockIdx):
//          seg0: Ahi⊗Whi  seg1: Ahi⊗Wlo  seg2: Alo⊗Whi; A=[x|t|t|pad|h|pad]
//          XCD-affinity swizzle: all 4 blocks sharing B-panel (bx,z) -> ids == same mod 8
// AMODE 2: conv gather: A[m][k=ks*1024+c] = hR[(tBase+tt+ks)%RING][b][c] * ldw[m][ks]
// EPI 0: fp32 partial store at zSel*splitStride (no bias)
// EPI 1: relu->bf16  2: sigmoid->bf16  3: rnn=TH*(v+bias)+h_t->bf16  4: out sigmoid fp32
template<int WR, int WC, int AMODE, int EPI>
__global__ __launch_bounds__(WR * WC * 64) void mm_kernel(
    const ushort* __restrict__ A, const float* __restrict__ xf,
    const float* __restrict__ tf, const ushort* __restrict__ hR,
    const ushort* __restrict__ hLo,
    const ushort* __restrict__ BT, const float* __restrict__ bias,
    void* __restrict__ Cp, const float* __restrict__ ldw,
    const ushort* __restrict__ TH, float* __restrict__ outp,
    int splitStride, int ldaA, int ldb, int ldc, int K, int t, int RING, int tBase)
{
    constexpr int BM = WR * 64, BN = WC * 64, NT = WR * WC * 64, LS = 72;
    constexpr int AIT = BM * 8 / NT, BIT = BN * 8 / NT;
    __shared__ ushort As[BM * LS];
    __shared__ ushort Bs[BN * LS];
    const int tid = threadIdx.x;
    const int lane = tid & 63, wave = tid >> 6;
    const int wr = wave / WC, wc = wave % WC;

    int bx, by, zSel = 0, kBase = 0;
    if (AMODE == 1) {
        int vid = blockIdx.x;
        int xcd = vid & 7, q = vid >> 3;
        int mem = q & 3, slot = q >> 2;
        int g = slot * 8 + xcd;            // g in [0,99): panel id = z*33 + bx
        if (g >= 99) return;
        zSel = g / 33; bx = g % 33; by = mem;
        kBase = zSel * KSEG;
    } else {
        bx = blockIdx.x; by = blockIdx.y;
    }
    const int m0 = by * BM, n0 = bx * BN;
    f32x4 acc[4][4] = {};

    auto gather = [&](int ktl, short8* vA, short8* vB) {
#pragma unroll
        for (int i = 0; i < AIT; ++i) {
            int id = tid + i * NT;
            int r = id >> 3, cc = id & 7;
            int k = ktl + cc * 8;          // segment-local k
            short8 v;
            if (AMODE == 0) {
                v = *(const short8*)(A + (size_t)(m0 + r) * ldaA + k);
            } else if (AMODE == 1) {
                bool lo = (zSel == 2);
                if (k < 288) {
                    float xv[8];
                    int b = m0 + r;
                    if (k < 256) {
                        const float* src = xf + ((size_t)b * TT + t) * INW + k;
#pragma unroll
                        for (int j = 0; j < 8; ++j) xv[j] = src[j];
                    } else if (k == 256) {
                        float tv = tf[(size_t)b * TT + t];
                        xv[0] = tv; xv[1] = tv;
#pragma unroll
                        for (int j = 2; j < 8; ++j) xv[j] = 0.f;
                    } else {
#pragma unroll
                        for (int j = 0; j < 8; ++j) xv[j] = 0.f;
                    }
                    ushort* po = (ushort*)&v;
#pragma unroll
                    for (int j = 0; j < 8; ++j) {
                        ushort hi = f2bf(xv[j]);
                        po[j] = lo ? f2bf(xv[j] - bf2f(hi)) : hi;
                    }
                } else if (k < 1312) {
                    const ushort* src = lo
                        ? hLo + (size_t)(m0 + r) * HH + (k - 288)
                        : hR + (size_t)((t + 8) % RING) * BH + (size_t)(m0 + r) * HH + (k - 288);
                    v = *(const short8*)src;
                } else {
                    ushort* pz = (ushort*)&v;
#pragma unroll
                    for (int j = 0; j < 8; ++j) pz[j] = 0;
                }
            } else {  // AMODE 2: conv gather
                int ks = k >> 10, c = k & 1023;
                int tt = m0 >> 8, b = (m0 & 255) + r;
                int slot = (tBase + tt + ks) % RING;
                short8 hv = *(const short8*)(hR + (size_t)slot * BH + (size_t)b * HH + c);
                float s = ldw[((size_t)tt * 256 + b) * CSW + ks];
                ushort* pv = (ushort*)&hv;
                ushort* po = (ushort*)&v;
#pragma unroll
                for (int j = 0; j < 8; ++j) po[j] = f2bf(bf2f(pv[j]) * s);
            }
            vA[i] = v;
        }
#pragma unroll
        for (int i = 0; i < BIT; ++i) {
            int id = tid + i * NT;
            int n = id >> 3, cc = id & 7;
            vB[i] = *(const short8*)(BT + (size_t)(n0 + n) * ldb + kBase + ktl + cc * 8);
        }
    };

    short8 vA[AIT], vB[BIT];
    gather(0, vA, vB);

    for (int kt = 0; kt < K; kt += 64) {
        // stow current regs to LDS
#pragma unroll
        for (int i = 0; i < AIT; ++i) {
            int id = tid + i * NT;
            *(short8*)(As + (id >> 3) * LS + (id & 7) * 8) = vA[i];
        }
#pragma unroll
        for (int i = 0; i < BIT; ++i) {
            int id = tid + i * NT;
            *(short8*)(Bs + (id >> 3) * LS + (id & 7) * 8) = vB[i];
        }
        __syncthreads();
        // prefetch next tile (global latency hides under MFMA below)
        if (kt + 64 < K) gather(kt + 64, vA, vB);
        // compute
#pragma unroll
        for (int kf = 0; kf < 2; ++kf) {
            short8 aF[4], bF[4];
#pragma unroll
            for (int mi = 0; mi < 4; ++mi)
                aF[mi] = *(const short8*)(As + (wr * 64 + mi * 16 + (lane & 15)) * LS + kf * 32 + (lane >> 4) * 8);
#pragma unroll
            for (int ni = 0; ni < 4; ++ni)
                bF[ni] = *(const short8*)(Bs + (wc * 64 + ni * 16 + (lane & 15)) * LS + kf * 32 + (lane >> 4) * 8);
#pragma unroll
            for (int mi = 0; mi < 4; ++mi)
#pragma unroll
                for (int ni = 0; ni < 4; ++ni)
                    acc[mi][ni] = __builtin_amdgcn_mfma_f32_16x16x32_bf16(aF[mi], bF[ni], acc[mi][ni], 0, 0, 0);
        }
        __syncthreads();
    }
    // ---- epilogue ----
#pragma unroll
    for (int mi = 0; mi < 4; ++mi) {
#pragma unroll
        for (int ni = 0; ni < 4; ++ni) {
#pragma unroll
            for (int j = 0; j < 4; ++j) {
                int row = m0 + wr * 64 + mi * 16 + ((lane >> 4) << 2) + j;
                int col = n0 + wc * 64 + ni * 16 + (lane & 15);
                float v = acc[mi][ni][j];
                if (EPI != 0 && bias) v += bias[col];
                if (EPI == 0) {
                    ((float*)Cp)[(size_t)zSel * splitStride + (size_t)row * ldc + col] = v;
                } else if (EPI == 1) {
                    ((ushort*)Cp)[(size_t)row * ldc + col] = f2bf(v > 0.f ? v : 0.f);
                } else if (EPI == 2) {
                    ((ushort*)Cp)[(size_t)row * ldc + col] = f2bf(sigf(v));
                } else if (EPI == 3) {
                    int tt = row >> 8, b = row & 255;
                    int slot = (tBase + tt + 9) % RING;
                    float th = bf2f(TH[(size_t)row * HH + col]);
                    float h  = bf2f(hR[(size_t)slot * BH + (size_t)b * HH + col]);
                    ((ushort*)Cp)[(size_t)row * ldc + col] = f2bf(th * v + h);
                } else {
                    int tt = tBase + (row >> 8), b = row & 255;
                    outp[((size_t)b * TT + tt) * OUTW + col] = sigf(v);
                }
            }
        }
    }
}

// ================= weight prep =================
__global__ void build_wct(const float* __restrict__ kw, const float* __restrict__ rw,
                          ushort* __restrict__ WcT)
{
    size_t i = (size_t)blockIdx.x * 256 + threadIdx.x;
    if (i >= (size_t)NPAD * KTRIP) return;
    int n = (int)(i / KTRIP), k = (int)(i % KTRIP);
    int sel = k / KSEG, kr = k - sel * KSEG;
    float w = 0.f;
    if (n < GG) {
        if (kr < 256)           w = kw[(size_t)kr * GG + n];
        else if (kr == 256)     w = kw[(size_t)256 * GG + n];
        else if (kr == 257)     w = rw[(size_t)1024 * GG + n];
        else if (kr >= 288 && kr < 1312) w = rw[(size_t)(kr - 288) * GG + n];
    }
    ushort hi = f2bf(w);
    WcT[i] = (sel == 1) ? f2bf(w - bf2f(hi)) : hi;
}

__global__ void build_bc(const float* __restrict__ kb, const float* __restrict__ rb,
                         float* __restrict__ bc)
{
    int i = blockIdx.x * 256 + threadIdx.x;
    if (i < NPAD) bc[i] = (i < GG) ? kb[i] + rb[i] : 0.f;
}

__global__ void build_ctt(const float* __restrict__ cw, ushort* __restrict__ ctT)
{
    size_t i = (size_t)blockIdx.x * 256 + threadIdx.x;
    if (i >= (size_t)HH * HH * CSW) return;
    int o = (int)(i / (HH * CSW)), rest = (int)(i % (HH * CSW));
    int k = rest >> 10, c = rest & 1023;
    ctT[i] = f2bf(cw[((size_t)o * HH + c) * CSW + k]);
}

__global__ void build_swt(const float* __restrict__ sw, const float* __restrict__ sb,
                          ushort* __restrict__ swT, float* __restrict__ sbP)
{
    int i = blockIdx.x * 256 + threadIdx.x;
    if (i < 256 * 1024) {
        int n = i >> 10, k = i & 1023;
        swT[i] = f2bf(n < 170 ? sw[(size_t)k * 170 + n] : 0.f);
    }
    if (i < 256) sbP[i] = (i < 170) ? sb[i] : 0.f;
}

__global__ void build_rswt(const float* __restrict__ rsw, ushort* __restrict__ rswT)
{
    int i = blockIdx.x * 256 + threadIdx.x;
    if (i >= 1024 * 256) return;
    int n = i >> 8, k = i & 255;
    rswT[i] = f2bf(k < 170 ? rsw[(size_t)k * HH + n] : 0.f);
}

__global__ void build_owt(const float* __restrict__ ow, ushort* __restrict__ owT)
{
    int i = blockIdx.x * 256 + threadIdx.x;
    if (i >= OUTW * HH) return;
    int n = i >> 10, k = i & 1023;
    owT[i] = f2bf(ow[(size_t)k * OUTW + n]);
}

// ================= per-step pointwise (sums 3 split-K partials + bias) ============
__global__ __launch_bounds__(256) void step_kernel(
    const float* __restrict__ xoP, const float* __restrict__ bc,
    float* __restrict__ c, ushort* __restrict__ hR, ushort* __restrict__ hLo,
    float* __restrict__ dist, int t, int RING)
{
    const size_t S = (size_t)BB * NPAD;
    int b = blockIdx.x, tid = threadIdx.x;
    const float* x0 = xoP + (size_t)b * NPAD;
    __shared__ float fm[LL], im[LL];
    if (tid == 0) {
        float xr[2 * LL];
        for (int l = 0; l < 2 * LL; ++l) xr[l] = x0[l] + x0[S + l] + x0[2 * S + l] + bc[l];
        float m1 = -1e30f, m2 = -1e30f;
        for (int l = 0; l < LL; ++l) { m1 = fmaxf(m1, xr[l]); m2 = fmaxf(m2, xr[LL + l]); }
        float e1[LL], e2[LL], s1 = 0.f, s2 = 0.f;
        for (int l = 0; l < LL; ++l) {
            e1[l] = expf(xr[l] - m1); s1 += e1[l];
            e2[l] = expf(xr[LL + l] - m2); s2 += e2[l];
        }
        float cum = 0.f, mean = 0.f;
        for (int l = 0; l < LL; ++l) { cum += e1[l] / s1; fm[l] = cum; mean += cum; }
        float rc = 0.f;
        for (int l = LL - 1; l >= 0; --l) { rc += e2[l] / s2; im[l] = rc; }
        dist[(size_t)t * BB + b] = 1.0f - mean / LL;
    }
    __syncthreads();
    int slot = (t + 9) % RING;
    for (int e = tid; e < HH; e += 256) {
        int l = e >> 7;
        int c0 = 2 * LL + e;
        float f  = sigf(x0[c0] + x0[S + c0] + x0[2 * S + c0] + bc[c0]);
        int c1 = c0 + HH;
        float ig = sigf(x0[c1] + x0[S + c1] + x0[2 * S + c1] + bc[c1]);
        int c2 = c1 + HH;
        float og = sigf(x0[c2] + x0[S + c2] + x0[2 * S + c2] + bc[c2]);
        int c3 = c2 + HH;
        float ci = tanhf(x0[c3] + x0[S + c3] + x0[2 * S + c3] + bc[c3]);
        size_t idx = (size_t)b * HH + e;
        float cl = c[idx];
        float F = fm[l], I = im[l], OV = F * I;
        float cn = OV * (f * cl + ig * ci) + (F - OV) * cl + (I - OV) * ci;
        float hn = og * tanhf(cn);
        c[idx] = cn;
        ushort hi = f2bf(hn);
        hR[(size_t)slot * BH + idx] = hi;
        hLo[idx] = f2bf(hn - bf2f(hi));
    }
}

// ================= chunk helpers =================
__global__ void ld_chunk_kernel(const float* __restrict__ dist, float* __restrict__ ldC,
                                int tBase, int Mloc)
{
    int id = blockIdx.x * 256 + threadIdx.x;
    if (id >= Mloc) return;
    int t = tBase + (id >> 8), b = id & 255;
    float cv[CSW], cum = 0.f, mx = -1e30f;
#pragma unroll
    for (int k = 0; k < CSW; ++k) {
        int ts = t - 9 + k;
        cum += (ts >= 0) ? dist[(size_t)ts * BB + b] : 0.f;
        cv[k] = cum; mx = fmaxf(mx, cum);
    }
    float ss = 0.f;
#pragma unroll
    for (int k = 0; k < CSW; ++k) { cv[k] = expf(cv[k] - mx); ss += cv[k]; }
    float inv = 1.0f / ss;
#pragma unroll
    for (int k = 0; k < CSW; ++k) ldC[(size_t)id * CSW + k] = cv[k] * inv;
}

__global__ void mlh_kernel(const ushort* __restrict__ hR, const float* __restrict__ ldC,
                           ushort* __restrict__ MLH, int tBase, int RING)
{
    size_t id = (size_t)blockIdx.x * 256 + threadIdx.x;   // over Mloc*128
    int m = (int)(id >> 7);
    int c0 = ((int)(id & 127)) << 3;
    int t = tBase + (m >> 8), b = m & 255;
    float acc[8] = {};
#pragma unroll
    for (int k = 0; k < CSW; ++k) {
        float s = ldC[(size_t)m * CSW + k];
        int slot = (t + k) % RING;
        short8 hv = *(const short8*)(hR + (size_t)slot * BH + (size_t)b * HH + c0);
        ushort* pv = (ushort*)&hv;
#pragma unroll
        for (int j = 0; j < 8; ++j) acc[j] += bf2f(pv[j]) * s;
    }
#pragma unroll
    for (int j = 0; j < 8; ++j) MLH[(size_t)m * HH + c0 + j] = f2bf(acc[j] * 0.1f);
}

// ================= launch =================
extern "C" void kernel_launch(void* const* d_in, const int* in_sizes, int n_in,
                              void* d_out, int out_size, void* d_ws, size_t ws_size,
                              hipStream_t stream)
{
    const float* x   = (const float*)d_in[0];
    const float* tim = (const float*)d_in[1];
    const float* kw  = (const float*)d_in[2];
    const float* kb  = (const float*)d_in[3];
    const float* rw  = (const float*)d_in[4];
    const float* rb  = (const float*)d_in[5];
    const float* sw  = (const float*)d_in[6];
    const float* sb  = (const float*)d_in[7];
    const float* rsw = (const float*)d_in[8];
    const float* rsb = (const float*)d_in[9];
    const float* cw  = (const float*)d_in[10];
    const float* cb  = (const float*)d_in[11];
    const float* ow  = (const float*)d_in[12];
    const float* ob  = (const float*)d_in[13];
    float* out  = (float*)d_out;
    float* dist = out + (size_t)BB * TT * OUTW;

    // ---- adaptive chunk size against ws_size ----
    auto planSize = [&](int tch) -> size_t {
        size_t o = 0;
        auto al = [&](size_t bytes) { o += (bytes + 255) & ~(size_t)255; };
        int ring = tch + 9;
        al((size_t)ring * BH * 2);             // hRing
        al((size_t)BH * 2);                    // hLo
        al((size_t)BH * 4);                    // c
        al((size_t)NPAD * KTRIP * 2);          // WcT
        al((size_t)NPAD * 4);                  // bc
        al((size_t)3 * BB * NPAD * 4);         // xoP (3 split-K partials)
        al((size_t)tch * 256 * CSW * 4);       // ldC
        al((size_t)HH * HH * CSW * 2);         // ctT
        al((size_t)256 * 1024 * 2);            // swT
        al((size_t)256 * 4);                   // sbP
        al((size_t)1024 * 256 * 2);            // rswT
        al((size_t)OUTW * HH * 2);             // owT
        al((size_t)tch * 256 * HH * 2);        // MLH / RNN
        al((size_t)tch * 256 * 256 * 2);       // TH1
        al((size_t)tch * 256 * HH * 2);        // TH
        return o;
    };
    const int cands[5] = {64, 32, 16, 8, 4};
    int TCH = 0;
    for (int ci = 0; ci < 5; ++ci)
        if (planSize(cands[ci]) <= ws_size) { TCH = cands[ci]; break; }
    if (TCH == 0) return;   // diagnostic: output stays zero -> absmax ~0.83
    const int RING = TCH + 9;
    const int Mloc = TCH * 256;

    char* base = (char*)d_ws;
    size_t off = 0;
    auto alloc = [&](size_t bytes) { char* p = base + off; off += (bytes + 255) & ~(size_t)255; return p; };
    ushort* hRing = (ushort*)alloc((size_t)RING * BH * 2);
    ushort* hLo   = (ushort*)alloc((size_t)BH * 2);
    float*  c     = (float*) alloc((size_t)BH * 4);
    ushort* WcT   = (ushort*)alloc((size_t)NPAD * KTRIP * 2);
    float*  bc    = (float*) alloc((size_t)NPAD * 4);
    float*  xoP   = (float*) alloc((size_t)3 * BB * NPAD * 4);
    float*  ldC   = (float*) alloc((size_t)TCH * 256 * CSW * 4);
    ushort* ctT   = (ushort*)alloc((size_t)HH * HH * CSW * 2);
    ushort* swT   = (ushort*)alloc((size_t)256 * 1024 * 2);
    float*  sbP   = (float*) alloc((size_t)256 * 4);
    ushort* rswT  = (ushort*)alloc((size_t)1024 * 256 * 2);
    ushort* owT   = (ushort*)alloc((size_t)OUTW * HH * 2);
    ushort* MLH   = (ushort*)alloc((size_t)TCH * 256 * HH * 2);
    ushort* TH1   = (ushort*)alloc((size_t)TCH * 256 * 256 * 2);
    ushort* TH    = (ushort*)alloc((size_t)TCH * 256 * HH * 2);
    ushort* RNN   = MLH;

    // state init
    hipMemsetAsync(hRing, 0, (size_t)9 * BH * 2, stream);
    hipMemsetAsync(hLo, 0, (size_t)BH * 2, stream);
    hipMemsetAsync(c, 0, (size_t)BH * 4, stream);

    // weight prep
    build_wct<<<(int)(((size_t)NPAD * KTRIP + 255) / 256), 256, 0, stream>>>(kw, rw, WcT);
    build_bc<<<(NPAD + 255) / 256, 256, 0, stream>>>(kb, rb, bc);
    build_ctt<<<(int)(((size_t)HH * HH * CSW + 255) / 256), 256, 0, stream>>>(cw, ctT);
    build_swt<<<(256 * 1024 + 255) / 256, 256, 0, stream>>>(sw, sb, swT, sbP);
    build_rswt<<<(1024 * 256 + 255) / 256, 256, 0, stream>>>(rsw, rswT);
    build_owt<<<(OUTW * HH + 255) / 256, 256, 0, stream>>>(ow, owT);

    const int SPLIT_STRIDE = BB * NPAD;

    for (int tBase = 0; tBase < TT; tBase += TCH) {
        // ---- scan steps of this chunk ----
        for (int t = tBase; t < tBase + TCH; ++t) {
            // 416 swizzled blocks: 99 panels (bx,z) x 4 M-tiles, panel-mates same XCD
            mm_kernel<1, 2, 1, 0><<<dim3(416), 128, 0, stream>>>(
                nullptr, x, tim, hRing, hLo, WcT, nullptr, xoP, nullptr, nullptr, nullptr,
                SPLIT_STRIDE, 0, KTRIP, NPAD, KSEG, t, RING, 0);
            step_kernel<<<BB, 256, 0, stream>>>(xoP, bc, c, hRing, hLo, dist, t, RING);
        }
        // ---- batched phase-2 for this chunk ----
        ld_chunk_kernel<<<Mloc / 256, 256, 0, stream>>>(dist, ldC, tBase, Mloc);
        mlh_kernel<<<Mloc / 2, 256, 0, stream>>>(hRing, ldC, MLH, tBase, RING);
        // theme1 = relu(MLH @ scale_w + sb)   [Mloc x 256(pad170) x K1024]
        mm_kernel<2, 2, 0, 1><<<dim3(2, Mloc / 128), 256, 0, stream>>>(
            MLH, nullptr, nullptr, nullptr, nullptr, swT, sbP, TH1, nullptr, nullptr, nullptr,
            0, 1024, 1024, 256, 1024, 0, RING, tBase);
        // theme = sigmoid(TH1 @ rescale_w + rsb)  [Mloc x 1024 x K256]
        mm_kernel<2, 2, 0, 2><<<dim3(8, Mloc / 128), 256, 0, stream>>>(
            TH1, nullptr, nullptr, nullptr, nullptr, rswT, rsb, TH, nullptr, nullptr, nullptr,
            0, 256, 256, 1024, 256, 0, RING, tBase);
        // rnn = TH*(conv+cb) + h   [Mloc x 1024 x K10240], A gathered on the fly
        mm_kernel<2, 2, 2, 3><<<dim3(8, Mloc / 128), 256, 0, stream>>>(
            nullptr, nullptr, nullptr, hRing, nullptr, ctT, cb, RNN, ldC, TH, nullptr,
            0, 0, HH * CSW, 1024, HH * CSW, 0, RING, tBase);
        // output = sigmoid(RNN @ out_w + ob)  [Mloc x 64 x K1024]
        mm_kernel<4, 1, 0, 4><<<dim3(1, Mloc / 256), 256, 0, stream>>>(
            RNN, nullptr, nullptr, nullptr, nullptr, owT, ob, nullptr, nullptr, nullptr, out,
            0, 1024, 1024, 0, 1024, 0, RING, tBase);
    }
}

// Round 5
// 12380.049 us; speedup vs baseline: 18.2552x; 1.1503x over previous
//
#include <hip/hip_runtime.h>
#include <hip/hip_bf16.h>
#include <math.h>

#define BB 256
#define TT 256
#define INW 256
#define HH 1024
#define LL 8
#define CSW 10
#define OUTW 64
#define GG 4112
#define KSEG 1344          // 288 (x,t,t,pad) + 1024 (h) + 32 pad
#define NPAD 4224          // 4112 padded to 33*128
#define BH (BB * HH)
#define NPANEL 66          // 33 Whi + 33 Wlo panels (N-tile x W-select)

typedef __attribute__((ext_vector_type(8))) short short8;
typedef __attribute__((ext_vector_type(4))) float f32x4;

__device__ __forceinline__ float bf2f(ushort u) {
    union { float f; unsigned int i; } v; v.i = ((unsigned int)u) << 16; return v.f;
}
__device__ __forceinline__ ushort f2bf(float f) {
    __hip_bfloat16 h = __float2bfloat16(f);      // native RTNE cvt on gfx950
    return *(ushort*)&h;
}
__device__ __forceinline__ float sigf(float v) { return 1.0f / (1.0f + expf(-v)); }

// ================= generic bf16 MFMA GEMM, reg-prefetch double-buffered ==========
// C(MxN) = epilogue(A(MxK)*B(KxN) + bias);  B passed TRANSPOSED: BT[N][K].
// AMODE 0: plain bf16 A (rows contiguous at ldaA)
// AMODE 1: recurrent gather at step t. Panel-pinned swizzle:
//          panel p in [0,66): p<33 -> Whi N-tile p (members z0,z2 x by0,by1)
//                             p>=33 -> Wlo N-tile p-33 (members z1 x by0,by1)
//          XCD = p%8 every step -> W stays resident in that XCD's L2.
//          z0: hHi x Whi   z1: hHi x Wlo   z2: hLo x Whi;  A = [x|t|t|pad|h|pad]
// AMODE 2: conv gather: A[m][k=ks*1024+c] = hR[(tBase+tt+ks)%RING][b][c] * ldw[m][ks]
// EPI 0: fp32 partial store at zSel*splitStride (no bias)
// EPI 1: relu->bf16  2: sigmoid->bf16  3: rnn=TH*(v+bias)+h_t->bf16  4: out sigmoid fp32
template<int WR, int WC, int AMODE, int EPI>
__global__ __launch_bounds__(WR * WC * 64) void mm_kernel(
    const ushort* __restrict__ A, const float* __restrict__ xf,
    const float* __restrict__ tf, const ushort* __restrict__ hR,
    const ushort* __restrict__ hLo,
    const ushort* __restrict__ BT, const float* __restrict__ bias,
    void* __restrict__ Cp, const float* __restrict__ ldw,
    const ushort* __restrict__ TH, float* __restrict__ outp,
    int splitStride, int ldaA, int ldb, int ldc, int K, int t, int RING, int tBase)
{
    constexpr int BM = WR * 64, BN = WC * 64, NT = WR * WC * 64, LS = 72;
    constexpr int AIT = BM * 8 / NT, BIT = BN * 8 / NT;
    __shared__ ushort As[BM * LS];
    __shared__ ushort Bs[BN * LS];
    const int tid = threadIdx.x;
    const int lane = tid & 63, wave = tid >> 6;
    const int wr = wave / WC, wc = wave % WC;

    int bx, by, zSel = 0;
    const ushort* BTeff = BT;
    if (AMODE == 1) {
        // panel-pinned mapping: xcd = vid&7 serves panels p == xcd (mod 8)
        int vid = blockIdx.x;
        int xcd = vid & 7, q = vid >> 3;
        int p = -1, mem = 0;
        for (int j = 0; ; ++j) {
            int pp = xcd + 8 * j;
            if (pp >= NPANEL) break;
            int cc = (pp < 33) ? 4 : 2;
            if (q < cc) { p = pp; mem = q; break; }
            q -= cc;
        }
        if (p < 0) return;
        if (p < 33) { bx = p;      zSel = (mem < 2) ? 0 : 2; by = mem & 1; BTeff = BT; }
        else        { bx = p - 33; zSel = 1;                 by = mem & 1; BTeff = A;  }
    } else {
        bx = blockIdx.x; by = blockIdx.y;
    }
    const int m0 = by * BM, n0 = bx * BN;
    f32x4 acc[4][4] = {};

    auto gather = [&](int ktl, short8* vA, short8* vB) {
#pragma unroll
        for (int i = 0; i < AIT; ++i) {
            int id = tid + i * NT;
            int r = id >> 3, cc = id & 7;
            int k = ktl + cc * 8;          // segment-local k
            short8 v;
            if (AMODE == 0) {
                v = *(const short8*)(A + (size_t)(m0 + r) * ldaA + k);
            } else if (AMODE == 1) {
                bool lo = (zSel == 2);
                if (k < 288) {
                    float xv[8];
                    int b = m0 + r;
                    if (k < 256) {
                        const float* src = xf + ((size_t)b * TT + t) * INW + k;
#pragma unroll
                        for (int j = 0; j < 8; ++j) xv[j] = src[j];
                    } else if (k == 256) {
                        float tv = tf[(size_t)b * TT + t];
                        xv[0] = tv; xv[1] = tv;
#pragma unroll
                        for (int j = 2; j < 8; ++j) xv[j] = 0.f;
                    } else {
#pragma unroll
                        for (int j = 0; j < 8; ++j) xv[j] = 0.f;
                    }
                    ushort* po = (ushort*)&v;
#pragma unroll
                    for (int j = 0; j < 8; ++j) {
                        ushort hi = f2bf(xv[j]);
                        po[j] = lo ? f2bf(xv[j] - bf2f(hi)) : hi;
                    }
                } else if (k < 1312) {
                    const ushort* src = lo
                        ? hLo + (size_t)(m0 + r) * HH + (k - 288)
                        : hR + (size_t)((t + 8) % RING) * BH + (size_t)(m0 + r) * HH + (k - 288);
                    v = *(const short8*)src;
                } else {
                    ushort* pz = (ushort*)&v;
#pragma unroll
                    for (int j = 0; j < 8; ++j) pz[j] = 0;
                }
            } else {  // AMODE 2: conv gather
                int ks = k >> 10, c = k & 1023;
                int tt = m0 >> 8, b = (m0 & 255) + r;
                int slot = (tBase + tt + ks) % RING;
                short8 hv = *(const short8*)(hR + (size_t)slot * BH + (size_t)b * HH + c);
                float s = ldw[((size_t)tt * 256 + b) * CSW + ks];
                ushort* pv = (ushort*)&hv;
                ushort* po = (ushort*)&v;
#pragma unroll
                for (int j = 0; j < 8; ++j) po[j] = f2bf(bf2f(pv[j]) * s);
            }
            vA[i] = v;
        }
#pragma unroll
        for (int i = 0; i < BIT; ++i) {
            int id = tid + i * NT;
            int n = id >> 3, cc = id & 7;
            vB[i] = *(const short8*)(BTeff + (size_t)(n0 + n) * ldb + ktl + cc * 8);
        }
    };

    short8 vA[AIT], vB[BIT];
    gather(0, vA, vB);

    for (int kt = 0; kt < K; kt += 64) {
        // stow current regs to LDS
#pragma unroll
        for (int i = 0; i < AIT; ++i) {
            int id = tid + i * NT;
            *(short8*)(As + (id >> 3) * LS + (id & 7) * 8) = vA[i];
        }
#pragma unroll
        for (int i = 0; i < BIT; ++i) {
            int id = tid + i * NT;
            *(short8*)(Bs + (id >> 3) * LS + (id & 7) * 8) = vB[i];
        }
        __syncthreads();
        // prefetch next tile (global latency hides under MFMA below)
        if (kt + 64 < K) gather(kt + 64, vA, vB);
        // compute
#pragma unroll
        for (int kf = 0; kf < 2; ++kf) {
            short8 aF[4], bF[4];
#pragma unroll
            for (int mi = 0; mi < 4; ++mi)
                aF[mi] = *(const short8*)(As + (wr * 64 + mi * 16 + (lane & 15)) * LS + kf * 32 + (lane >> 4) * 8);
#pragma unroll
            for (int ni = 0; ni < 4; ++ni)
                bF[ni] = *(const short8*)(Bs + (wc * 64 + ni * 16 + (lane & 15)) * LS + kf * 32 + (lane >> 4) * 8);
#pragma unroll
            for (int mi = 0; mi < 4; ++mi)
#pragma unroll
                for (int ni = 0; ni < 4; ++ni)
                    acc[mi][ni] = __builtin_amdgcn_mfma_f32_16x16x32_bf16(aF[mi], bF[ni], acc[mi][ni], 0, 0, 0);
        }
        __syncthreads();
    }
    // ---- epilogue ----
#pragma unroll
    for (int mi = 0; mi < 4; ++mi) {
#pragma unroll
        for (int ni = 0; ni < 4; ++ni) {
#pragma unroll
            for (int j = 0; j < 4; ++j) {
                int row = m0 + wr * 64 + mi * 16 + ((lane >> 4) << 2) + j;
                int col = n0 + wc * 64 + ni * 16 + (lane & 15);
                float v = acc[mi][ni][j];
                if (EPI != 0 && bias) v += bias[col];
                if (EPI == 0) {
                    ((float*)Cp)[(size_t)zSel * splitStride + (size_t)row * ldc + col] = v;
                } else if (EPI == 1) {
                    ((ushort*)Cp)[(size_t)row * ldc + col] = f2bf(v > 0.f ? v : 0.f);
                } else if (EPI == 2) {
                    ((ushort*)Cp)[(size_t)row * ldc + col] = f2bf(sigf(v));
                } else if (EPI == 3) {
                    int tt = row >> 8, b = row & 255;
                    int slot = (tBase + tt + 9) % RING;
                    float th = bf2f(TH[(size_t)row * HH + col]);
                    float h  = bf2f(hR[(size_t)slot * BH + (size_t)b * HH + col]);
                    ((ushort*)Cp)[(size_t)row * ldc + col] = f2bf(th * v + h);
                } else {
                    int tt = tBase + (row >> 8), b = row & 255;
                    outp[((size_t)b * TT + tt) * OUTW + col] = sigf(v);
                }
            }
        }
    }
}

// ================= weight prep =================
// WhiT[n][k], WloT[n][k]: k<256: kw[k][n]; k==256: kw[256][n]; k==257: rw[1024][n];
// 288<=k<1312: rw[k-288][n]; else 0.  hi=RTNE(w), lo=RTNE(w-hi).
__global__ void build_whl(const float* __restrict__ kw, const float* __restrict__ rw,
                          ushort* __restrict__ WhiT, ushort* __restrict__ WloT)
{
    size_t i = (size_t)blockIdx.x * 256 + threadIdx.x;
    if (i >= (size_t)NPAD * KSEG) return;
    int n = (int)(i / KSEG), k = (int)(i % KSEG);
    float w = 0.f;
    if (n < GG) {
        if (k < 256)           w = kw[(size_t)k * GG + n];
        else if (k == 256)     w = kw[(size_t)256 * GG + n];
        else if (k == 257)     w = rw[(size_t)1024 * GG + n];
        else if (k >= 288 && k < 1312) w = rw[(size_t)(k - 288) * GG + n];
    }
    ushort hi = f2bf(w);
    WhiT[i] = hi;
    WloT[i] = f2bf(w - bf2f(hi));
}

__global__ void build_bc(const float* __restrict__ kb, const float* __restrict__ rb,
                         float* __restrict__ bc)
{
    int i = blockIdx.x * 256 + threadIdx.x;
    if (i < NPAD) bc[i] = (i < GG) ? kb[i] + rb[i] : 0.f;
}

__global__ void build_ctt(const float* __restrict__ cw, ushort* __restrict__ ctT)
{
    size_t i = (size_t)blockIdx.x * 256 + threadIdx.x;
    if (i >= (size_t)HH * HH * CSW) return;
    int o = (int)(i / (HH * CSW)), rest = (int)(i % (HH * CSW));
    int k = rest >> 10, c = rest & 1023;
    ctT[i] = f2bf(cw[((size_t)o * HH + c) * CSW + k]);
}

__global__ void build_swt(const float* __restrict__ sw, const float* __restrict__ sb,
                          ushort* __restrict__ swT, float* __restrict__ sbP)
{
    int i = blockIdx.x * 256 + threadIdx.x;
    if (i < 256 * 1024) {
        int n = i >> 10, k = i & 1023;
        swT[i] = f2bf(n < 170 ? sw[(size_t)k * 170 + n] : 0.f);
    }
    if (i < 256) sbP[i] = (i < 170) ? sb[i] : 0.f;
}

__global__ void build_rswt(const float* __restrict__ rsw, ushort* __restrict__ rswT)
{
    int i = blockIdx.x * 256 + threadIdx.x;
    if (i >= 1024 * 256) return;
    int n = i >> 8, k = i & 255;
    rswT[i] = f2bf(k < 170 ? rsw[(size_t)k * HH + n] : 0.f);
}

__global__ void build_owt(const float* __restrict__ ow, ushort* __restrict__ owT)
{
    int i = blockIdx.x * 256 + threadIdx.x;
    if (i >= OUTW * HH) return;
    int n = i >> 10, k = i & 1023;
    owT[i] = f2bf(ow[(size_t)k * OUTW + n]);
}

// ================= per-step pointwise (sums 3 split-K partials + bias) ============
__global__ __launch_bounds__(256) void step_kernel(
    const float* __restrict__ xoP, const float* __restrict__ bc,
    float* __restrict__ c, ushort* __restrict__ hR, ushort* __restrict__ hLo,
    float* __restrict__ dist, int t, int RING)
{
    const size_t S = (size_t)BB * NPAD;
    int b = blockIdx.x, tid = threadIdx.x;
    const float* x0 = xoP + (size_t)b * NPAD;
    __shared__ float fm[LL], im[LL];
    if (tid == 0) {
        float xr[2 * LL];
        for (int l = 0; l < 2 * LL; ++l) xr[l] = x0[l] + x0[S + l] + x0[2 * S + l] + bc[l];
        float m1 = -1e30f, m2 = -1e30f;
        for (int l = 0; l < LL; ++l) { m1 = fmaxf(m1, xr[l]); m2 = fmaxf(m2, xr[LL + l]); }
        float e1[LL], e2[LL], s1 = 0.f, s2 = 0.f;
        for (int l = 0; l < LL; ++l) {
            e1[l] = expf(xr[l] - m1); s1 += e1[l];
            e2[l] = expf(xr[LL + l] - m2); s2 += e2[l];
        }
        float cum = 0.f, mean = 0.f;
        for (int l = 0; l < LL; ++l) { cum += e1[l] / s1; fm[l] = cum; mean += cum; }
        float rc = 0.f;
        for (int l = LL - 1; l >= 0; --l) { rc += e2[l] / s2; im[l] = rc; }
        dist[(size_t)t * BB + b] = 1.0f - mean / LL;
    }
    __syncthreads();
    int slot = (t + 9) % RING;
    for (int e = tid; e < HH; e += 256) {
        int l = e >> 7;
        int c0 = 2 * LL + e;
        float f  = sigf(x0[c0] + x0[S + c0] + x0[2 * S + c0] + bc[c0]);
        int c1 = c0 + HH;
        float ig = sigf(x0[c1] + x0[S + c1] + x0[2 * S + c1] + bc[c1]);
        int c2 = c1 + HH;
        float og = sigf(x0[c2] + x0[S + c2] + x0[2 * S + c2] + bc[c2]);
        int c3 = c2 + HH;
        float ci = tanhf(x0[c3] + x0[S + c3] + x0[2 * S + c3] + bc[c3]);
        size_t idx = (size_t)b * HH + e;
        float cl = c[idx];
        float F = fm[l], I = im[l], OV = F * I;
        float cn = OV * (f * cl + ig * ci) + (F - OV) * cl + (I - OV) * ci;
        float hn = og * tanhf(cn);
        c[idx] = cn;
        ushort hi = f2bf(hn);
        hR[(size_t)slot * BH + idx] = hi;
        hLo[idx] = f2bf(hn - bf2f(hi));
    }
}

// ================= chunk helpers =================
__global__ void ld_chunk_kernel(const float* __restrict__ dist, float* __restrict__ ldC,
                                int tBase, int Mloc)
{
    int id = blockIdx.x * 256 + threadIdx.x;
    if (id >= Mloc) return;
    int t = tBase + (id >> 8), b = id & 255;
    float cv[CSW], cum = 0.f, mx = -1e30f;
#pragma unroll
    for (int k = 0; k < CSW; ++k) {
        int ts = t - 9 + k;
        cum += (ts >= 0) ? dist[(size_t)ts * BB + b] : 0.f;
        cv[k] = cum; mx = fmaxf(mx, cum);
    }
    float ss = 0.f;
#pragma unroll
    for (int k = 0; k < CSW; ++k) { cv[k] = expf(cv[k] - mx); ss += cv[k]; }
    float inv = 1.0f / ss;
#pragma unroll
    for (int k = 0; k < CSW; ++k) ldC[(size_t)id * CSW + k] = cv[k] * inv;
}

__global__ void mlh_kernel(const ushort* __restrict__ hR, const float* __restrict__ ldC,
                           ushort* __restrict__ MLH, int tBase, int RING)
{
    size_t id = (size_t)blockIdx.x * 256 + threadIdx.x;   // over Mloc*128
    int m = (int)(id >> 7);
    int c0 = ((int)(id & 127)) << 3;
    int t = tBase + (m >> 8), b = m & 255;
    float acc[8] = {};
#pragma unroll
    for (int k = 0; k < CSW; ++k) {
        float s = ldC[(size_t)m * CSW + k];
        int slot = (t + k) % RING;
        short8 hv = *(const short8*)(hR + (size_t)slot * BH + (size_t)b * HH + c0);
        ushort* pv = (ushort*)&hv;
#pragma unroll
        for (int j = 0; j < 8; ++j) acc[j] += bf2f(pv[j]) * s;
    }
#pragma unroll
    for (int j = 0; j < 8; ++j) MLH[(size_t)m * HH + c0 + j] = f2bf(acc[j] * 0.1f);
}

// ================= launch =================
extern "C" void kernel_launch(void* const* d_in, const int* in_sizes, int n_in,
                              void* d_out, int out_size, void* d_ws, size_t ws_size,
                              hipStream_t stream)
{
    const float* x   = (const float*)d_in[0];
    const float* tim = (const float*)d_in[1];
    const float* kw  = (const float*)d_in[2];
    const float* kb  = (const float*)d_in[3];
    const float* rw  = (const float*)d_in[4];
    const float* rb  = (const float*)d_in[5];
    const float* sw  = (const float*)d_in[6];
    const float* sb  = (const float*)d_in[7];
    const float* rsw = (const float*)d_in[8];
    const float* rsb = (const float*)d_in[9];
    const float* cw  = (const float*)d_in[10];
    const float* cb  = (const float*)d_in[11];
    const float* ow  = (const float*)d_in[12];
    const float* ob  = (const float*)d_in[13];
    float* out  = (float*)d_out;
    float* dist = out + (size_t)BB * TT * OUTW;

    // ---- adaptive chunk size against ws_size ----
    auto planSize = [&](int tch) -> size_t {
        size_t o = 0;
        auto al = [&](size_t bytes) { o += (bytes + 255) & ~(size_t)255; };
        int ring = tch + 9;
        al((size_t)ring * BH * 2);             // hRing
        al((size_t)BH * 2);                    // hLo
        al((size_t)BH * 4);                    // c
        al((size_t)NPAD * KSEG * 2);           // WhiT
        al((size_t)NPAD * KSEG * 2);           // WloT
        al((size_t)NPAD * 4);                  // bc
        al((size_t)3 * BB * NPAD * 4);         // xoP (3 split partials)
        al((size_t)tch * 256 * CSW * 4);       // ldC
        al((size_t)HH * HH * CSW * 2);         // ctT
        al((size_t)256 * 1024 * 2);            // swT
        al((size_t)256 * 4);                   // sbP
        al((size_t)1024 * 256 * 2);            // rswT
        al((size_t)OUTW * HH * 2);             // owT
        al((size_t)tch * 256 * HH * 2);        // MLH / RNN
        al((size_t)tch * 256 * 256 * 2);       // TH1
        al((size_t)tch * 256 * HH * 2);        // TH
        return o;
    };
    const int cands[5] = {64, 32, 16, 8, 4};
    int TCH = 0;
    for (int ci = 0; ci < 5; ++ci)
        if (planSize(cands[ci]) <= ws_size) { TCH = cands[ci]; break; }
    if (TCH == 0) return;   // diagnostic: output stays zero -> absmax ~0.83
    const int RING = TCH + 9;
    const int Mloc = TCH * 256;

    char* base = (char*)d_ws;
    size_t off = 0;
    auto alloc = [&](size_t bytes) { char* p = base + off; off += (bytes + 255) & ~(size_t)255; return p; };
    ushort* hRing = (ushort*)alloc((size_t)RING * BH * 2);
    ushort* hLo   = (ushort*)alloc((size_t)BH * 2);
    float*  c     = (float*) alloc((size_t)BH * 4);
    ushort* WhiT  = (ushort*)alloc((size_t)NPAD * KSEG * 2);
    ushort* WloT  = (ushort*)alloc((size_t)NPAD * KSEG * 2);
    float*  bc    = (float*) alloc((size_t)NPAD * 4);
    float*  xoP   = (float*) alloc((size_t)3 * BB * NPAD * 4);
    float*  ldC   = (float*) alloc((size_t)TCH * 256 * CSW * 4);
    ushort* ctT   = (ushort*)alloc((size_t)HH * HH * CSW * 2);
    ushort* swT   = (ushort*)alloc((size_t)256 * 1024 * 2);
    float*  sbP   = (float*) alloc((size_t)256 * 4);
    ushort* rswT  = (ushort*)alloc((size_t)1024 * 256 * 2);
    ushort* owT   = (ushort*)alloc((size_t)OUTW * HH * 2);
    ushort* MLH   = (ushort*)alloc((size_t)TCH * 256 * HH * 2);
    ushort* TH1   = (ushort*)alloc((size_t)TCH * 256 * 256 * 2);
    ushort* TH    = (ushort*)alloc((size_t)TCH * 256 * HH * 2);
    ushort* RNN   = MLH;

    // state init
    hipMemsetAsync(hRing, 0, (size_t)9 * BH * 2, stream);
    hipMemsetAsync(hLo, 0, (size_t)BH * 2, stream);
    hipMemsetAsync(c, 0, (size_t)BH * 4, stream);

    // weight prep
    build_whl<<<(int)(((size_t)NPAD * KSEG + 255) / 256), 256, 0, stream>>>(kw, rw, WhiT, WloT);
    build_bc<<<(NPAD + 255) / 256, 256, 0, stream>>>(kb, rb, bc);
    build_ctt<<<(int)(((size_t)HH * HH * CSW + 255) / 256), 256, 0, stream>>>(cw, ctT);
    build_swt<<<(256 * 1024 + 255) / 256, 256, 0, stream>>>(sw, sb, swT, sbP);
    build_rswt<<<(1024 * 256 + 255) / 256, 256, 0, stream>>>(rsw, rswT);
    build_owt<<<(OUTW * HH + 255) / 256, 256, 0, stream>>>(ow, owT);

    const int SPLIT_STRIDE = BB * NPAD;

    for (int tBase = 0; tBase < TT; tBase += TCH) {
        // ---- scan steps of this chunk ----
        for (int t = tBase; t < tBase + TCH; ++t) {
            // 224 panel-pinned blocks (66 panels x 4/2 members, XCD = panel%8)
            mm_kernel<2, 2, 1, 0><<<dim3(224), 256, 0, stream>>>(
                WloT, x, tim, hRing, hLo, WhiT, nullptr, xoP, nullptr, nullptr, nullptr,
                SPLIT_STRIDE, 0, KSEG, NPAD, KSEG, t, RING, 0);
            step_kernel<<<BB, 256, 0, stream>>>(xoP, bc, c, hRing, hLo, dist, t, RING);
        }
        // ---- batched phase-2 for this chunk ----
        ld_chunk_kernel<<<Mloc / 256, 256, 0, stream>>>(dist, ldC, tBase, Mloc);
        mlh_kernel<<<Mloc / 2, 256, 0, stream>>>(hRing, ldC, MLH, tBase, RING);
        // theme1 = relu(MLH @ scale_w + sb)   [Mloc x 256(pad170) x K1024]
        mm_kernel<2, 2, 0, 1><<<dim3(2, Mloc / 128), 256, 0, stream>>>(
            MLH, nullptr, nullptr, nullptr, nullptr, swT, sbP, TH1, nullptr, nullptr, nullptr,
            0, 1024, 1024, 256, 1024, 0, RING, tBase);
        // theme = sigmoid(TH1 @ rescale_w + rsb)  [Mloc x 1024 x K256]
        mm_kernel<2, 2, 0, 2><<<dim3(8, Mloc / 128), 256, 0, stream>>>(
            TH1, nullptr, nullptr, nullptr, nullptr, rswT, rsb, TH, nullptr, nullptr, nullptr,
            0, 256, 256, 1024, 256, 0, RING, tBase);
        // rnn = TH*(conv+cb) + h   [Mloc x 1024 x K10240], A gathered on the fly
        mm_kernel<2, 2, 2, 3><<<dim3(8, Mloc / 128), 256, 0, stream>>>(
            nullptr, nullptr, nullptr, hRing, nullptr, ctT, cb, RNN, ldC, TH, nullptr,
            0, 0, HH * CSW, 1024, HH * CSW, 0, RING, tBase);
        // output = sigmoid(RNN @ out_w + ob)  [Mloc x 64 x K1024]
        mm_kernel<4, 1, 0, 4><<<dim3(1, Mloc / 256), 256, 0, stream>>>(
            RNN, nullptr, nullptr, nullptr, nullptr, owT, ob, nullptr, nullptr, nullptr, out,
            0, 1024, 1024, 0, 1024, 0, RING, tBase);
    }
}